// Round 5
// baseline (2155.982 us; speedup 1.0000x reference)
//
#include <hip/hip_runtime.h>
#include <hip/hip_bf16.h>

#define N_NODES 50000
#define N_EDGES 800000
#define D 128
#define L_LAYERS 3
#define BN_EPS 1e-5f
#define NBUK 196          // buckets of 256 dst values: 196*256 = 50176 >= 50000
#define BIN_CHUNK 4096    // edges per block in bin: 196*4096 >= 800000
#define NBIN_BLOCKS 196
#define BSTRIDE 5120      // fixed per-bucket bin region (words); max bucket ~4350
#define AROW 68           // LDS row stride in words (16B aligned, low conflicts)
#define ASTRIDE 33        // agg LDS tile row stride (floats): conflict-free col reads
#define NPART 16          // BN stat partial buffers (atomic contention spread)
#define PADOFF (N_NODES << 8)   // byte offset of the zero pad row

typedef __attribute__((ext_vector_type(8))) short short8;
typedef __attribute__((ext_vector_type(4))) float floatx4;
typedef __attribute__((ext_vector_type(4))) unsigned uintx4;

__device__ __forceinline__ unsigned short f2bf(float f) {
    unsigned u = __builtin_bit_cast(unsigned, f);
    u += 0x7FFFu + ((u >> 16) & 1u);   // round-to-nearest-even
    return (unsigned short)(u >> 16);
}
__device__ __forceinline__ float bf2f(unsigned short h) {
    unsigned u = ((unsigned)h) << 16;
    return __builtin_bit_cast(float, u);
}
__device__ __forceinline__ float bf2f_lo(unsigned p) {
    return __builtin_bit_cast(float, p << 16);
}
__device__ __forceinline__ float bf2f_hi(unsigned p) {
    return __builtin_bit_cast(float, p & 0xFFFF0000u);
}
// packed f32x2 -> bf16x2 (RNE), single HW instruction; no builtin on gfx950
__device__ __forceinline__ unsigned cvtpk(float lo, float hi) {
    unsigned r;
    asm("v_cvt_pk_bf16_f32 %0, %1, %2" : "=v"(r) : "v"(lo), "v"(hi));
    return r;
}

__device__ __forceinline__ int edge_at(const void* ei, const int* flag64, long long i) {
    if (*flag64) return (int)((const long long*)ei)[i];
    return ((const int*)ei)[i];
}

// ---------------------------------------------------------------------------
// Merged one-time prep: block 0 detects i64-vs-i32 edge layout, zeroes the
// counter/stats region and the pad row of xb; blocks 1..48 permute weights
// into MFMA B-fragment bf16 layout; remaining blocks convert x -> bf16.
__global__ __launch_bounds__(256) void prep_kernel(const float* __restrict__ x,
        const void* __restrict__ ei, int* __restrict__ flag,
        const float* __restrict__ W1, const float* __restrict__ W2,
        short* __restrict__ Wp, unsigned short* __restrict__ xb,
        unsigned* __restrict__ zreg, int zwords) {
    int bid = blockIdx.x;
    int t = threadIdx.x;
    if (bid == 0) {
        __shared__ int nz;
        if (t == 0) nz = 0;
        __syncthreads();
        if (((const int*)ei)[2 * t + 1] != 0) atomicAdd(&nz, 1);
        __syncthreads();
        if (t == 0) *flag = (nz == 0) ? 1 : 0;
        for (int i = t; i < zwords; i += 256) zreg[i] = 0u;
        if (t < 64) ((unsigned*)(xb + (size_t)N_NODES * D))[t] = 0u;  // zero pad row
    } else if (bid <= 48) {
        int tid = (bid - 1) * 256 + t;   // 6*2048 total
        int mat = tid >> 11;
        int t2 = tid & 2047;
        int kt = t2 >> 9;
        int nt = (t2 >> 6) & 7;
        int lane = t2 & 63;
        const float* W = (mat < 3) ? (W1 + (size_t)mat * D * D)
                                   : (W2 + (size_t)(mat - 3) * D * D);
        int kbase = kt * 32 + (lane >> 4) * 8;
        int n = nt * 16 + (lane & 15);
        unsigned fw[4];
        #pragma unroll
        for (int j = 0; j < 4; j++)
            fw[j] = cvtpk(W[(kbase + 2 * j) * D + n], W[(kbase + 2 * j + 1) * D + n]);
        *(uint4*)(Wp + (size_t)mat * D * D + (size_t)t2 * 8) =
            make_uint4(fw[0], fw[1], fw[2], fw[3]);
    } else {
        long long i = (long long)((bid - 49) * 256 + t) * 4;
        float4 v = *(const float4*)(x + i);
        unsigned w0 = cvtpk(v.x, v.y);
        unsigned w1 = cvtpk(v.z, v.w);
        *(uint2*)(xb + i) = make_uint2(w0, w1);
    }
}

// ---------------------------------------------------------------------------
// CSR stage 1 (merged count+bin): single pass. Each block histograms its
// 4096 edges in LDS, reserves per-bucket ranges in FIXED-stride regions via
// global cursors (cursor final value == bucket count), writes packed words.
// word = (src << 8) | (dst & 255).  This is the ONLY edge indexing structure
// now: the aggregate kernel consumes binned directly (edge-parallel).
__global__ __launch_bounds__(256) void bin_kernel(const void* __restrict__ ei,
        const int* __restrict__ flag64, int* __restrict__ bucketCursor,
        unsigned* __restrict__ binned) {
    __shared__ int lhist[NBUK];
    __shared__ int gbase[NBUK];
    int t = threadIdx.x;
    for (int i = t; i < NBUK; i += 256) lhist[i] = 0;
    __syncthreads();

    int e0 = blockIdx.x * BIN_CHUNK;
    unsigned w[BIN_CHUNK / 256];
    short bkt[BIN_CHUNK / 256];
    short lidx[BIN_CHUNK / 256];
    #pragma unroll
    for (int i = 0; i < BIN_CHUNK / 256; i++) {
        int e = e0 + t + i * 256;
        if (e < N_EDGES) {
            int s = edge_at(ei, flag64, e);
            int d = edge_at(ei, flag64, (long long)N_EDGES + e);
            int b = d >> 8;
            w[i] = ((unsigned)s << 8) | (unsigned)(d & 255);
            bkt[i] = (short)b;
            lidx[i] = (short)atomicAdd(&lhist[b], 1);
        } else {
            bkt[i] = -1;
        }
    }
    __syncthreads();
    for (int i = t; i < NBUK; i += 256) {
        int c = lhist[i];
        gbase[i] = i * BSTRIDE + (c ? atomicAdd(&bucketCursor[i], c) : 0);
    }
    __syncthreads();
    #pragma unroll
    for (int i = 0; i < BIN_CHUNK / 256; i++) {
        if (bkt[i] >= 0)
            binned[gbase[bkt[i]] + (int)lidx[i]] = w[i];
    }
}

// ---------------------------------------------------------------------------
// Edge-parallel, XCD-affine sliced aggregation. Block = (bucket, col-slice);
// slice = bid & 3 so each XCD (bid & 7 round-robin) touches ONE 32-col slice
// of x (3.2 MB -> L2-resident). Threads process 4 edges/round: read packed
// (src<<8|dstLocal) words from binned, load 16 B of the slice, fp32
// atomic-accumulate into a [256][33] LDS tile (conflict-light), then write
// the bucket slice to agg with coalesced stores. All-blocks-resident (784).
__global__ __launch_bounds__(256, 4) void aggregate_kernel(
        const unsigned short* __restrict__ xb,
        const int* __restrict__ bucketCursor,
        const unsigned* __restrict__ binned,
        float* __restrict__ agg) {
    __shared__ float tile[256 * ASTRIDE];   // 33.8 KB
    int t = threadIdx.x;
    int slice = blockIdx.x & 3;
    int b = blockIdx.x >> 2;
    const char* xbase = (const char*)xb;

    #pragma unroll
    for (int i = 0; i < ASTRIDE; i++) tile[t + i * 256] = 0.f;
    __syncthreads();

    int cnt = bucketCursor[b];
    const unsigned* eb = binned + (size_t)b * BSTRIDE;
    int sub = t & 3;
    unsigned soff = (unsigned)(slice << 6) + (unsigned)(sub << 4);

#define ADD8(ew, xv) { \
    float* tp = tile + (int)((ew) & 255u) * ASTRIDE + (sub << 3); \
    atomicAdd(tp + 0, bf2f_lo((xv).x)); atomicAdd(tp + 1, bf2f_hi((xv).x)); \
    atomicAdd(tp + 2, bf2f_lo((xv).y)); atomicAdd(tp + 3, bf2f_hi((xv).y)); \
    atomicAdd(tp + 4, bf2f_lo((xv).z)); atomicAdd(tp + 5, bf2f_hi((xv).z)); \
    atomicAdd(tp + 6, bf2f_lo((xv).w)); atomicAdd(tp + 7, bf2f_hi((xv).w)); }

    for (int i0 = (t >> 2); i0 < cnt; i0 += 256) {
        unsigned e0 = eb[i0];
        unsigned e1 = (i0 + 64  < cnt) ? eb[i0 + 64]  : (unsigned)PADOFF;
        unsigned e2 = (i0 + 128 < cnt) ? eb[i0 + 128] : (unsigned)PADOFF;
        unsigned e3 = (i0 + 192 < cnt) ? eb[i0 + 192] : (unsigned)PADOFF;
        uint4 v0 = *(const uint4*)(xbase + (e0 & 0xFFFFFF00u) + soff);
        uint4 v1 = *(const uint4*)(xbase + (e1 & 0xFFFFFF00u) + soff);
        uint4 v2 = *(const uint4*)(xbase + (e2 & 0xFFFFFF00u) + soff);
        uint4 v3 = *(const uint4*)(xbase + (e3 & 0xFFFFFF00u) + soff);
        ADD8(e0, v0); ADD8(e1, v1); ADD8(e2, v2); ADD8(e3, v3);
    }
#undef ADD8
    __syncthreads();

    // write-out: 8192 floats, lanes sweep cols fastest (coalesced 128B runs)
    int nb = b * 256;
    #pragma unroll
    for (int k = 0; k < 32; k++) {
        int idx = k * 256 + t;
        int row = idx >> 5, c = idx & 31;
        agg[(size_t)(nb + row) * D + (slice << 5) + c] = tile[row * ASTRIDE + c];
    }
}

// ---------------------------------------------------------------------------
// Normalize + GEMM1: streams agg (fp32, coalesced) + self x rows, computes
// both L2 norms, packs the bf16 A tile (only quantization point), then the
// 4-wave MFMA, BN partial stats, coalesced H store.
__global__ __launch_bounds__(256, 8) void norm_gemm1_kernel(
        const unsigned short* __restrict__ xb,
        const float* __restrict__ agg,
        const float* __restrict__ epsArr, int layer,
        const short* __restrict__ Wp, const float* __restrict__ bB,
        unsigned* __restrict__ Hout,      // bf16 pairs, 64 words per row
        float* __restrict__ gsum, float* __restrict__ gsq) {
    __shared__ __attribute__((aligned(16))) unsigned lA[16 * AROW];
    const char* xbase = (const char*)xb;
    int wave = threadIdx.x >> 6, lane = threadIdx.x & 63;
    int g = lane >> 4, p = lane & 15;
    int r0 = blockIdx.x * 16;
    float eps1 = 1.0f + epsArr[layer];
    int rw2 = threadIdx.x >> 4, pq2 = threadIdx.x & 15;

    // coalesced loads: aggregated row (fp32) + self row (bf16)
    uint4 sv = *(const uint4*)(xbase + (((unsigned)(r0 + rw2)) << 8) + (pq2 << 4));
    const float* ap = agg + (size_t)(r0 + rw2) * D + pq2 * 8;
    float4 q0 = *(const float4*)ap;
    float4 q1 = *(const float4*)(ap + 4);

    {
        float s[8];
        s[0] = q0.x; s[1] = q0.y; s[2] = q0.z; s[3] = q0.w;
        s[4] = q1.x; s[5] = q1.y; s[6] = q1.z; s[7] = q1.w;
        float xv[8];
        xv[0] = bf2f_lo(sv.x); xv[1] = bf2f_hi(sv.x);
        xv[2] = bf2f_lo(sv.y); xv[3] = bf2f_hi(sv.y);
        xv[4] = bf2f_lo(sv.z); xv[5] = bf2f_hi(sv.z);
        xv[6] = bf2f_lo(sv.w); xv[7] = bf2f_hi(sv.w);
        float sa = 0.f, sx = 0.f;
        #pragma unroll
        for (int k = 0; k < 8; k++) { sa += s[k] * s[k]; sx += xv[k] * xv[k]; }
        #pragma unroll
        for (int mm = 8; mm >= 1; mm >>= 1) {
            sa += __shfl_xor(sa, mm);
            sx += __shfl_xor(sx, mm);
        }
        float ra = 1.0f / fmaxf(sqrtf(sa), 1e-12f);
        float rx = eps1 / fmaxf(sqrtf(sx), 1e-12f);
        float o[8];
        #pragma unroll
        for (int k = 0; k < 8; k++) o[k] = s[k] * ra + xv[k] * rx;
        unsigned w0 = cvtpk(o[0], o[1]);
        unsigned w1 = cvtpk(o[2], o[3]);
        unsigned w2 = cvtpk(o[4], o[5]);
        unsigned w3 = cvtpk(o[6], o[7]);
        *(uint4*)(lA + rw2 * AROW + pq2 * 4) = make_uint4(w0, w1, w2, w3);
    }
    __syncthreads();

    // ---- MFMA phase: wave w covers cols [32w, 32w+32) via nt0/nt1 ----
    int m = p;
    int nt0 = wave * 2, nt1 = nt0 + 1;
    short8 afr[4];
    #pragma unroll
    for (int kt = 0; kt < 4; kt++)
        afr[kt] = *(const short8*)(lA + m * AROW + kt * 16 + g * 4);
    __syncthreads();   // all A-frag reads done; lA becomes the H staging tile

    floatx4 acc0 = (floatx4){0.f, 0.f, 0.f, 0.f};
    floatx4 acc1 = (floatx4){0.f, 0.f, 0.f, 0.f};
    #pragma unroll
    for (int kt = 0; kt < 4; kt++) {
        short8 bf0 = *(const short8*)(Wp + (size_t)((kt * 8 + nt0) * 64 + lane) * 8);
        short8 bf1 = *(const short8*)(Wp + (size_t)((kt * 8 + nt1) * 64 + lane) * 8);
        acc0 = __builtin_amdgcn_mfma_f32_16x16x32_bf16(afr[kt], bf0, acc0, 0, 0, 0);
        acc1 = __builtin_amdgcn_mfma_f32_16x16x32_bf16(afr[kt], bf1, acc1, 0, 0, 0);
    }

    unsigned short* hlds = (unsigned short*)lA;
    float bc0 = bB[nt0 * 16 + m], bc1 = bB[nt1 * 16 + m];
    float s0 = 0.f, q0s = 0.f, s1 = 0.f, q1s = 0.f;
    #pragma unroll
    for (int r = 0; r < 4; r++) {
        int lrow = g * 4 + r;
        float h0 = acc0[r] + bc0;
        float h1 = acc1[r] + bc1;
        hlds[lrow * (AROW * 2) + nt0 * 16 + m] = f2bf(h0);
        hlds[lrow * (AROW * 2) + nt1 * 16 + m] = f2bf(h1);
        s0 += h0; q0s += h0 * h0;
        s1 += h1; q1s += h1 * h1;
    }
    s0 += __shfl_xor(s0, 16); s0 += __shfl_xor(s0, 32);
    q0s += __shfl_xor(q0s, 16); q0s += __shfl_xor(q0s, 32);
    s1 += __shfl_xor(s1, 16); s1 += __shfl_xor(s1, 32);
    q1s += __shfl_xor(q1s, 16); q1s += __shfl_xor(q1s, 32);
    if (lane < 16) {
        float* gs = gsum + (size_t)(blockIdx.x & (NPART - 1)) * D;
        float* gq = gsq + (size_t)(blockIdx.x & (NPART - 1)) * D;
        atomicAdd(&gs[nt0 * 16 + m], s0);
        atomicAdd(&gs[nt1 * 16 + m], s1);
        atomicAdd(&gq[nt0 * 16 + m], q0s);
        atomicAdd(&gq[nt1 * 16 + m], q1s);
    }
    __syncthreads();

    // coalesced H store: 256 threads x one 16B chunk (16 rows x 16 chunks)
    {
        int crow = threadIdx.x >> 4;
        int cq = threadIdx.x & 15;
        uint4 v = *(const uint4*)(lA + crow * AROW + cq * 4);
        *(uint4*)(Hout + (size_t)(r0 + crow) * 64 + cq * 4) = v;
    }
}

// ---------------------------------------------------------------------------
// GEMM2 (MFMA bf16): Y = relu(scale*H+shift) @ W2 + b2, BN finalize fused
// (sums the NPART stat partials). Output tile staged in LDS, coalesced store.
__global__ __launch_bounds__(256) void gemm2_mfma_kernel(const unsigned short* __restrict__ H,
        const float* __restrict__ gsum, const float* __restrict__ gsq,
        const float* __restrict__ gamma, const float* __restrict__ beta,
        const short* __restrict__ Wp, const float* __restrict__ b,
        float* __restrict__ Yf32, unsigned* __restrict__ Yb16, int finalLayer) {
    __shared__ float s_scale[D];
    __shared__ float s_shift[D];
    __shared__ unsigned so[64 * 132];   // fp32 tile 64x132 or bf16 tile 64x68
    if (threadIdx.x < D) {
        int c = threadIdx.x;
        const float invN = 1.0f / (float)N_NODES;
        float su = 0.f, sq = 0.f;
        #pragma unroll
        for (int pp = 0; pp < NPART; pp++) {
            su += gsum[(size_t)pp * D + c];
            sq += gsq[(size_t)pp * D + c];
        }
        float mu = su * invN;
        float var = fmaxf(sq * invN - mu * mu, 0.f);
        float is = rsqrtf(var + BN_EPS);
        float sc = gamma[c] * is;
        s_scale[c] = sc;
        s_shift[c] = beta[c] - mu * sc;
    }
    __syncthreads();

    int wave = threadIdx.x >> 6, lane = threadIdx.x & 63;
    int r0 = blockIdx.x * 64;
    int m = lane & 15, g = lane >> 4;
    int arow = r0 + wave * 16 + m;
    bool valid = arow < N_NODES;

    short8 a[4];
    #pragma unroll
    for (int kt = 0; kt < 4; kt++) {
        int koff = kt * 32 + g * 8;
        if (valid) {
            short8 hv = *(const short8*)(H + (long long)arow * D + koff);
            unsigned aw[4];
            #pragma unroll
            for (int jj = 0; jj < 4; jj++) {
                float h0 = bf2f((unsigned short)hv[2 * jj]);
                float h1 = bf2f((unsigned short)hv[2 * jj + 1]);
                float v0 = fmaxf(h0 * s_scale[koff + 2 * jj] + s_shift[koff + 2 * jj], 0.f);
                float v1 = fmaxf(h1 * s_scale[koff + 2 * jj + 1] + s_shift[koff + 2 * jj + 1], 0.f);
                aw[jj] = cvtpk(v0, v1);
            }
            a[kt] = __builtin_bit_cast(short8, (uintx4){aw[0], aw[1], aw[2], aw[3]});
        } else {
            a[kt] = (short8)0;
        }
    }

    floatx4 acc[8];
    #pragma unroll
    for (int nt = 0; nt < 8; nt++) acc[nt] = (floatx4){0.f, 0.f, 0.f, 0.f};

    #pragma unroll
    for (int nt = 0; nt < 8; nt++) {
        #pragma unroll
        for (int kt = 0; kt < 4; kt++) {
            short8 bf = *(const short8*)(Wp + (size_t)((kt * 8 + nt) * 64 + lane) * 8);
            acc[nt] = __builtin_amdgcn_mfma_f32_16x16x32_bf16(a[kt], bf, acc[nt], 0, 0, 0);
        }
    }

    if (finalLayer) {
        float* sof = (float*)so;
        #pragma unroll
        for (int nt = 0; nt < 8; nt++) {
            int col = nt * 16 + m;
            float bcol = b[col];
            #pragma unroll
            for (int r = 0; r < 4; r++) {
                int lrow = wave * 16 + g * 4 + r;
                sof[lrow * 132 + col] = acc[nt][r] + bcol;
            }
        }
        __syncthreads();
        // 64 rows x 32 float4 chunks = 2048; 256 threads x 8
        #pragma unroll
        for (int k = 0; k < 8; k++) {
            int c = threadIdx.x + k * 256;
            int crow = c >> 5;
            int cq = c & 31;
            if (r0 + crow < N_NODES) {
                float4 v = *(const float4*)(sof + crow * 132 + cq * 4);
                *(float4*)(Yf32 + (size_t)(r0 + crow) * D + cq * 4) = v;
            }
        }
    } else {
        unsigned short* sos = (unsigned short*)so;
        #pragma unroll
        for (int nt = 0; nt < 8; nt++) {
            int col = nt * 16 + m;
            float bcol = b[col];
            #pragma unroll
            for (int r = 0; r < 4; r++) {
                int lrow = wave * 16 + g * 4 + r;
                sos[lrow * (AROW * 2) + col] = f2bf(fmaxf(acc[nt][r] + bcol, 0.f));
            }
        }
        __syncthreads();
        // 64 rows x 16 16B chunks = 1024; 256 threads x 4
        #pragma unroll
        for (int k = 0; k < 4; k++) {
            int c = threadIdx.x + k * 256;
            int crow = c >> 4;
            int cq = c & 15;
            if (r0 + crow < N_NODES) {
                uint4 v = *(const uint4*)(so + crow * AROW + cq * 4);
                *(uint4*)(Yb16 + (size_t)(r0 + crow) * 64 + cq * 4) = v;
            }
        }
    }
}

// ---------------------------------------------------------------------------
extern "C" void kernel_launch(void* const* d_in, const int* in_sizes, int n_in,
                              void* d_out, int out_size, void* d_ws, size_t ws_size,
                              hipStream_t stream) {
    const float* x      = (const float*)d_in[0];
    const void*  ei     = d_in[1];
    const float* W1     = (const float*)d_in[2];
    const float* b1     = (const float*)d_in[3];
    const float* gamma  = (const float*)d_in[4];
    const float* beta   = (const float*)d_in[5];
    const float* W2     = (const float*)d_in[6];
    const float* b2     = (const float*)d_in[7];
    const float* epsArr = (const float*)d_in[8];
    float* out = (float*)d_out;

    char* ws = (char*)d_ws;
    const size_t xbuf = (size_t)(N_NODES + 1) * D * sizeof(short);  // +1 pad row
    const size_t hbuf = (size_t)N_NODES * D * sizeof(short);
    unsigned short* Xb  = (unsigned short*)ws;                 // gather input (bf16)
    unsigned* H16       = (unsigned*)(ws + xbuf);              // gemm1 out (bf16 pairs)
    char* p             = ws + xbuf + hbuf;
    short* Wp       = (short*)p;         p += 6 * (size_t)D * D * sizeof(short);
    float* agg      = (float*)p;         p += (size_t)NBUK * 256 * D * sizeof(float);
    unsigned* binned= (unsigned*)p;      p += (size_t)NBUK * BSTRIDE * sizeof(unsigned);
    int* flag       = (int*)p;           p += sizeof(int);
    // zero region: bucketCursor[NBUK] + stats[L][2][NPART][D]
    char* zbase     = p;
    int* bucketCursor=(int*)p;           p += NBUK * sizeof(int);
    float* stats    = (float*)p;         p += (size_t)L_LAYERS * 2 * NPART * D * sizeof(float);
    int zwords      = (int)((p - zbase) / 4);

    // One-time prep: detect edge dtype, zero counters/stats/pad-row, permute
    // weights, convert x -> bf16.
    prep_kernel<<<1 + 48 + (N_NODES * D / 4) / 256, 256, 0, stream>>>(
        x, ei, flag, W1, W2, Wp, Xb, (unsigned*)zbase, zwords);

    // Edge binning (single pass; binned is consumed directly by aggregation).
    bin_kernel<<<NBIN_BLOCKS, 256, 0, stream>>>(ei, flag, bucketCursor, binned);

    const int g1Grid = N_NODES / 16;                 // 3125, exact (50000/16)
    const int g2Grid = (N_NODES + 63) / 64;
    for (int l = 0; l < L_LAYERS; l++) {
        int fin = (l == L_LAYERS - 1) ? 1 : 0;
        float* gsum = stats + (size_t)l * 2 * NPART * D;
        float* gsq  = gsum + (size_t)NPART * D;

        aggregate_kernel<<<NBUK * 4, 256, 0, stream>>>(
            Xb, bucketCursor, binned, agg);
        norm_gemm1_kernel<<<g1Grid, 256, 0, stream>>>(
            Xb, agg, epsArr, l,
            Wp + (size_t)l * D * D, b1 + (size_t)l * D,
            H16, gsum, gsq);
        gemm2_mfma_kernel<<<g2Grid, 256, 0, stream>>>(
            (const unsigned short*)H16, gsum, gsq,
            gamma + (size_t)l * D, beta + (size_t)l * D,
            Wp + (size_t)(3 + l) * D * D, b2 + (size_t)l * D,
            out, (unsigned*)Xb, fin);
    }
}

// Round 6
// 219.722 us; speedup vs baseline: 9.8123x; 9.8123x over previous
//
#include <hip/hip_runtime.h>
#include <hip/hip_bf16.h>

#define N_NODES 50000
#define N_EDGES 800000
#define D 128
#define L_LAYERS 3
#define BN_EPS 1e-5f
#define NBUK 196          // buckets of 256 dst values: 196*256 = 50176 >= 50000
#define BIN_CHUNK 4096    // edges per block in bin: 196*4096 >= 800000
#define NBIN_BLOCKS 196
#define BSTRIDE 5120      // fixed per-bucket bin region (words); max bucket ~4350
#define CSTRIDE 5376      // fixed per-bucket csr region (padded; max ~4350+768)
#define AROW 68           // LDS row stride in words (16B aligned, low conflicts)
#define NPART 8           // BN stat partial buffers (atomic contention spread)
#define PADOFF (N_NODES << 8)   // byte offset of the zero pad row

typedef __attribute__((ext_vector_type(8))) short short8;
typedef __attribute__((ext_vector_type(4))) float floatx4;
typedef __attribute__((ext_vector_type(4))) unsigned uintx4;

__device__ __forceinline__ unsigned short f2bf(float f) {
    unsigned u = __builtin_bit_cast(unsigned, f);
    u += 0x7FFFu + ((u >> 16) & 1u);   // round-to-nearest-even
    return (unsigned short)(u >> 16);
}
__device__ __forceinline__ float bf2f(unsigned short h) {
    unsigned u = ((unsigned)h) << 16;
    return __builtin_bit_cast(float, u);
}
__device__ __forceinline__ float bf2f_lo(unsigned p) {
    return __builtin_bit_cast(float, p << 16);
}
__device__ __forceinline__ float bf2f_hi(unsigned p) {
    return __builtin_bit_cast(float, p & 0xFFFF0000u);
}
// packed f32x2 -> bf16x2 (RNE), single HW instruction; no builtin on gfx950
__device__ __forceinline__ unsigned cvtpk(float lo, float hi) {
    unsigned r;
    asm("v_cvt_pk_bf16_f32 %0, %1, %2" : "=v"(r) : "v"(lo), "v"(hi));
    return r;
}

__device__ __forceinline__ int edge_at(const void* ei, const int* flag64, long long i) {
    if (*flag64) return (int)((const long long*)ei)[i];
    return ((const int*)ei)[i];
}

// ---------------------------------------------------------------------------
// Merged one-time prep: block 0 detects i64-vs-i32 edge layout, zeroes the
// counter/stats region and the pad row of xb; blocks 1..48 permute weights
// into MFMA B-fragment bf16 layout; remaining blocks convert x -> bf16.
__global__ __launch_bounds__(256) void prep_kernel(const float* __restrict__ x,
        const void* __restrict__ ei, int* __restrict__ flag,
        const float* __restrict__ W1, const float* __restrict__ W2,
        short* __restrict__ Wp, unsigned short* __restrict__ xb,
        unsigned* __restrict__ zreg, int zwords) {
    int bid = blockIdx.x;
    int t = threadIdx.x;
    if (bid == 0) {
        __shared__ int nz;
        if (t == 0) nz = 0;
        __syncthreads();
        if (((const int*)ei)[2 * t + 1] != 0) atomicAdd(&nz, 1);
        __syncthreads();
        if (t == 0) *flag = (nz == 0) ? 1 : 0;
        for (int i = t; i < zwords; i += 256) zreg[i] = 0u;
        if (t < 64) ((unsigned*)(xb + (size_t)N_NODES * D))[t] = 0u;  // zero pad row
    } else if (bid <= 48) {
        int tid = (bid - 1) * 256 + t;   // 6*2048 total
        int mat = tid >> 11;
        int t2 = tid & 2047;
        int kt = t2 >> 9;
        int nt = (t2 >> 6) & 7;
        int lane = t2 & 63;
        const float* W = (mat < 3) ? (W1 + (size_t)mat * D * D)
                                   : (W2 + (size_t)(mat - 3) * D * D);
        int kbase = kt * 32 + (lane >> 4) * 8;
        int n = nt * 16 + (lane & 15);
        unsigned fw[4];
        #pragma unroll
        for (int j = 0; j < 4; j++)
            fw[j] = cvtpk(W[(kbase + 2 * j) * D + n], W[(kbase + 2 * j + 1) * D + n]);
        *(uint4*)(Wp + (size_t)mat * D * D + (size_t)t2 * 8) =
            make_uint4(fw[0], fw[1], fw[2], fw[3]);
    } else {
        long long i = (long long)((bid - 49) * 256 + t) * 4;
        float4 v = *(const float4*)(x + i);
        unsigned w0 = cvtpk(v.x, v.y);
        unsigned w1 = cvtpk(v.z, v.w);
        *(uint2*)(xb + i) = make_uint2(w0, w1);
    }
}

// ---------------------------------------------------------------------------
// CSR stage 1 (merged count+bin): single pass. Each block histograms its
// 4096 edges in LDS, reserves per-bucket ranges in FIXED-stride regions via
// global cursors (cursor final value == bucket count), writes packed words.
// word = (src << 8) | (dst & 255).
__global__ __launch_bounds__(256) void bin_kernel(const void* __restrict__ ei,
        const int* __restrict__ flag64, int* __restrict__ bucketCursor,
        unsigned* __restrict__ binned) {
    __shared__ int lhist[NBUK];
    __shared__ int gbase[NBUK];
    int t = threadIdx.x;
    for (int i = t; i < NBUK; i += 256) lhist[i] = 0;
    __syncthreads();

    int e0 = blockIdx.x * BIN_CHUNK;
    unsigned w[BIN_CHUNK / 256];
    short bkt[BIN_CHUNK / 256];
    short lidx[BIN_CHUNK / 256];
    #pragma unroll
    for (int i = 0; i < BIN_CHUNK / 256; i++) {
        int e = e0 + t + i * 256;
        if (e < N_EDGES) {
            int s = edge_at(ei, flag64, e);
            int d = edge_at(ei, flag64, (long long)N_EDGES + e);
            int b = d >> 8;
            w[i] = ((unsigned)s << 8) | (unsigned)(d & 255);
            bkt[i] = (short)b;
            lidx[i] = (short)atomicAdd(&lhist[b], 1);
        } else {
            bkt[i] = -1;
        }
    }
    __syncthreads();
    for (int i = t; i < NBUK; i += 256) {
        int c = lhist[i];
        gbase[i] = i * BSTRIDE + (c ? atomicAdd(&bucketCursor[i], c) : 0);
    }
    __syncthreads();
    #pragma unroll
    for (int i = 0; i < BIN_CHUNK / 256; i++) {
        if (bkt[i] >= 0)
            binned[gbase[bkt[i]] + (int)lidx[i]] = w[i];
    }
}

// CSR stage 2: one block per bucket; fixed CSTRIDE region per bucket.
// Each row's entry list is padded to a multiple of 4 with the zero-row
// offset, and entries are stored as PRE-SHIFTED byte offsets (src<<8) so the
// gather needs only 32-bit adds. bucketEnd[b] records the padded end of the
// bucket (used as `end` for the last row of each bucket).
__global__ __launch_bounds__(256) void csr_build_kernel(const unsigned* __restrict__ binned,
        const int* __restrict__ bucketCursor, int* __restrict__ rowptr,
        int* __restrict__ bucketEnd, int* __restrict__ csr) {
    __shared__ int ls[256];
    __shared__ int lhist[256];
    __shared__ int lcur[256];
    int b = blockIdx.x, t = threadIdx.x;
    int n = bucketCursor[b];
    const unsigned* src = binned + (size_t)b * BSTRIDE;

    lhist[t] = 0;
    __syncthreads();
    for (int i = t; i < n; i += 256)
        atomicAdd(&lhist[src[i] & 255u], 1);
    __syncthreads();
    int c = lhist[t];
    int pc = (c + 3) & ~3;           // pad each row to a multiple of 4
    ls[t] = pc;
    __syncthreads();
    for (int off = 1; off < 256; off <<= 1) {
        int u = (t >= off) ? ls[t - off] : 0;
        __syncthreads();
        ls[t] += u;
        __syncthreads();
    }
    int excl = ls[t] - pc;
    int base = b * CSTRIDE;
    int dst = b * 256 + t;
    if (dst <= N_NODES) rowptr[dst] = base + excl;
    if (t == 0) bucketEnd[b] = base + ls[255];
    lcur[t] = excl;
    __syncthreads();
    for (int i = t; i < n; i += 256) {
        unsigned wv = src[i];
        int pos = atomicAdd(&lcur[wv & 255u], 1);
        csr[base + pos] = (int)(wv & 0xFFFFFF00u);   // src byte-offset (src<<8)
    }
    __syncthreads();
    // fill this row's pad slots with the zero-row offset
    for (int i = lcur[t]; i < excl + pc; i++)
        csr[base + i] = PADOFF;
}

// ---------------------------------------------------------------------------
// Fused gather + GEMM1. 256-thread block = 4 waves over a 16-row tile
// (dynamic row queue, R1-proven). Lane owns 2 columns (4 B). Inner loop:
// 16 edges per iteration = 16 independent dword loads in flight; CSR entries
// are pre-shifted byte offsets and rows are padded to x4 (pad -> zero row),
// so per edge: 1 shfl + 1 add + 1 load + 4 VALU. Epilogue: full-wave reduce,
// L2 norms, cvtpk pack into LDS A tile; 4-wave MFMA; BN partial stats;
// coalesced H store.
__global__ __launch_bounds__(256, 8) void gather_gemm1_kernel(
        const unsigned short* __restrict__ xb,
        const int* __restrict__ rowptr, const int* __restrict__ csr,
        const int* __restrict__ bucketEnd,
        const float* __restrict__ epsArr, int layer,
        const short* __restrict__ Wp, const float* __restrict__ bB,
        unsigned* __restrict__ Hout,      // bf16 pairs, 64 words per row
        float* __restrict__ gsum, float* __restrict__ gsq) {
    __shared__ __attribute__((aligned(16))) unsigned lA[16 * AROW];  // 4352 B
    __shared__ int wq;
    const char* xbase = (const char*)xb;
    int wave = threadIdx.x >> 6, lane = threadIdx.x & 63;
    unsigned po = (unsigned)(lane << 2);       // lane's 2-col byte offset
    int r0 = blockIdx.x * 16;
    float eps1 = 1.0f + epsArr[layer];
    if (threadIdx.x == 0) wq = 0;
    __syncthreads();

#define EDGE4(J) { \
    unsigned o0 = (unsigned)__shfl((int)iv, (J) + 0) + po; \
    unsigned o1 = (unsigned)__shfl((int)iv, (J) + 1) + po; \
    unsigned o2 = (unsigned)__shfl((int)iv, (J) + 2) + po; \
    unsigned o3 = (unsigned)__shfl((int)iv, (J) + 3) + po; \
    unsigned p0 = *(const unsigned*)(xbase + o0); \
    unsigned p1 = *(const unsigned*)(xbase + o1); \
    unsigned p2 = *(const unsigned*)(xbase + o2); \
    unsigned p3 = *(const unsigned*)(xbase + o3); \
    a0 += bf2f_lo(p0); a1 += bf2f_hi(p0); \
    b0 += bf2f_lo(p1); b1 += bf2f_hi(p1); \
    c0 += bf2f_lo(p2); c1 += bf2f_hi(p2); \
    d0 += bf2f_lo(p3); d1 += bf2f_hi(p3); }

    // ---- gather phase: dynamic row queue ----
    for (;;) {
        int r;
        if (lane == 0) r = atomicAdd(&wq, 1);
        r = __shfl(r, 0);
        if (r >= 16) break;
        int row = r0 + r;
        int beg = rowptr[row];
        int end = ((row & 255) == 255) ? bucketEnd[row >> 8] : rowptr[row + 1];
        float a0 = 0.f, a1 = 0.f, b0 = 0.f, b1 = 0.f;
        float c0 = 0.f, c1 = 0.f, d0 = 0.f, d1 = 0.f;
        for (int base = beg; base < end; base += 64) {
            int n = end - base;
            if (n > 64) n = 64;
            unsigned iv = (lane < n) ? (unsigned)csr[base + lane] : (unsigned)PADOFF;
            int j = 0;
            for (; j + 16 <= n; j += 16) {   // 16 dword loads in flight
                EDGE4(j) EDGE4(j + 4) EDGE4(j + 8) EDGE4(j + 12)
            }
            for (; j < n; j += 4) {          // residual (n is a multiple of 4)
                EDGE4(j)
            }
        }
        float ax = a0 + b0 + c0 + d0;
        float ay = a1 + b1 + c1 + d1;
        unsigned pself = *(const unsigned*)(xbase + (((unsigned)row << 8) + po));
        float xv0 = bf2f_lo(pself), xv1 = bf2f_hi(pself);
        float sa = ax * ax + ay * ay;
        float sx = xv0 * xv0 + xv1 * xv1;
        #pragma unroll
        for (int mm = 32; mm >= 1; mm >>= 1) {
            sa += __shfl_xor(sa, mm);
            sx += __shfl_xor(sx, mm);
        }
        float ra = 1.0f / fmaxf(sqrtf(sa), 1e-12f);
        float rx = eps1 / fmaxf(sqrtf(sx), 1e-12f);
        lA[r * AROW + lane] = cvtpk(ax * ra + xv0 * rx, ay * ra + xv1 * rx);
    }
#undef EDGE4
    __syncthreads();

    // ---- MFMA phase: wave w covers cols [32w, 32w+32) via nt0/nt1 ----
    int m = lane & 15, g = lane >> 4;
    int nt0 = wave * 2, nt1 = nt0 + 1;
    short8 afr[4];
    #pragma unroll
    for (int kt = 0; kt < 4; kt++)
        afr[kt] = *(const short8*)(lA + m * AROW + kt * 16 + g * 4);
    __syncthreads();   // all A-frag reads done; lA becomes the H staging tile

    floatx4 acc0 = (floatx4){0.f, 0.f, 0.f, 0.f};
    floatx4 acc1 = (floatx4){0.f, 0.f, 0.f, 0.f};
    #pragma unroll
    for (int kt = 0; kt < 4; kt++) {
        short8 bf0 = *(const short8*)(Wp + (size_t)((kt * 8 + nt0) * 64 + lane) * 8);
        short8 bf1 = *(const short8*)(Wp + (size_t)((kt * 8 + nt1) * 64 + lane) * 8);
        acc0 = __builtin_amdgcn_mfma_f32_16x16x32_bf16(afr[kt], bf0, acc0, 0, 0, 0);
        acc1 = __builtin_amdgcn_mfma_f32_16x16x32_bf16(afr[kt], bf1, acc1, 0, 0, 0);
    }

    unsigned short* hlds = (unsigned short*)lA;
    float bc0 = bB[nt0 * 16 + m], bc1 = bB[nt1 * 16 + m];
    float s0 = 0.f, q0 = 0.f, s1 = 0.f, q1 = 0.f;
    #pragma unroll
    for (int r = 0; r < 4; r++) {
        int lrow = g * 4 + r;
        float h0 = acc0[r] + bc0;
        float h1 = acc1[r] + bc1;
        hlds[lrow * (AROW * 2) + nt0 * 16 + m] = f2bf(h0);
        hlds[lrow * (AROW * 2) + nt1 * 16 + m] = f2bf(h1);
        s0 += h0; q0 += h0 * h0;
        s1 += h1; q1 += h1 * h1;
    }
    s0 += __shfl_xor(s0, 16); s0 += __shfl_xor(s0, 32);
    q0 += __shfl_xor(q0, 16); q0 += __shfl_xor(q0, 32);
    s1 += __shfl_xor(s1, 16); s1 += __shfl_xor(s1, 32);
    q1 += __shfl_xor(q1, 16); q1 += __shfl_xor(q1, 32);
    if (lane < 16) {
        float* gs = gsum + (size_t)(blockIdx.x & (NPART - 1)) * D;
        float* gq = gsq + (size_t)(blockIdx.x & (NPART - 1)) * D;
        atomicAdd(&gs[nt0 * 16 + m], s0);
        atomicAdd(&gs[nt1 * 16 + m], s1);
        atomicAdd(&gq[nt0 * 16 + m], q0);
        atomicAdd(&gq[nt1 * 16 + m], q1);
    }
    __syncthreads();

    // coalesced H store: 256 threads x one 16B chunk (16 rows x 16 chunks)
    {
        int crow = threadIdx.x >> 4;
        int cq = threadIdx.x & 15;
        uint4 v = *(const uint4*)(lA + crow * AROW + cq * 4);
        *(uint4*)(Hout + (size_t)(r0 + crow) * 64 + cq * 4) = v;
    }
}

// ---------------------------------------------------------------------------
// GEMM2 mid-layer variant: Y = relu(scale*H+shift) @ W2 + b2 -> bf16 (next
// layer's x). Small LDS (17.4 KB) -> 8 blocks/CU.
__global__ __launch_bounds__(256, 8) void gemm2_mid_kernel(const unsigned short* __restrict__ H,
        const float* __restrict__ gsum, const float* __restrict__ gsq,
        const float* __restrict__ gamma, const float* __restrict__ beta,
        const short* __restrict__ Wp, const float* __restrict__ b,
        unsigned* __restrict__ Yb16) {
    __shared__ float s_scale[D];
    __shared__ float s_shift[D];
    __shared__ unsigned so[64 * AROW];   // bf16 tile 64 x 136 (17408 B)
    if (threadIdx.x < D) {
        int c = threadIdx.x;
        const float invN = 1.0f / (float)N_NODES;
        float su = 0.f, sq = 0.f;
        #pragma unroll
        for (int pp = 0; pp < NPART; pp++) {
            su += gsum[(size_t)pp * D + c];
            sq += gsq[(size_t)pp * D + c];
        }
        float mu = su * invN;
        float var = fmaxf(sq * invN - mu * mu, 0.f);
        float is = rsqrtf(var + BN_EPS);
        float sc = gamma[c] * is;
        s_scale[c] = sc;
        s_shift[c] = beta[c] - mu * sc;
    }
    __syncthreads();

    int wave = threadIdx.x >> 6, lane = threadIdx.x & 63;
    int r0 = blockIdx.x * 64;
    int m = lane & 15, g = lane >> 4;
    int arow = r0 + wave * 16 + m;
    bool valid = arow < N_NODES;

    short8 a[4];
    #pragma unroll
    for (int kt = 0; kt < 4; kt++) {
        int koff = kt * 32 + g * 8;
        if (valid) {
            short8 hv = *(const short8*)(H + (long long)arow * D + koff);
            unsigned aw[4];
            #pragma unroll
            for (int jj = 0; jj < 4; jj++) {
                float h0 = bf2f((unsigned short)hv[2 * jj]);
                float h1 = bf2f((unsigned short)hv[2 * jj + 1]);
                float v0 = fmaxf(h0 * s_scale[koff + 2 * jj] + s_shift[koff + 2 * jj], 0.f);
                float v1 = fmaxf(h1 * s_scale[koff + 2 * jj + 1] + s_shift[koff + 2 * jj + 1], 0.f);
                aw[jj] = cvtpk(v0, v1);
            }
            a[kt] = __builtin_bit_cast(short8, (uintx4){aw[0], aw[1], aw[2], aw[3]});
        } else {
            a[kt] = (short8)0;
        }
    }

    floatx4 acc[8];
    #pragma unroll
    for (int nt = 0; nt < 8; nt++) acc[nt] = (floatx4){0.f, 0.f, 0.f, 0.f};
    #pragma unroll
    for (int nt = 0; nt < 8; nt++) {
        #pragma unroll
        for (int kt = 0; kt < 4; kt++) {
            short8 bf = *(const short8*)(Wp + (size_t)((kt * 8 + nt) * 64 + lane) * 8);
            acc[nt] = __builtin_amdgcn_mfma_f32_16x16x32_bf16(a[kt], bf, acc[nt], 0, 0, 0);
        }
    }

    unsigned short* sos = (unsigned short*)so;
    #pragma unroll
    for (int nt = 0; nt < 8; nt++) {
        int col = nt * 16 + m;
        float bcol = b[col];
        #pragma unroll
        for (int r = 0; r < 4; r++) {
            int lrow = wave * 16 + g * 4 + r;
            sos[lrow * (AROW * 2) + col] = f2bf(fmaxf(acc[nt][r] + bcol, 0.f));
        }
    }
    __syncthreads();
    // 64 rows x 16 16B chunks = 1024; 256 threads x 4
    #pragma unroll
    for (int k = 0; k < 4; k++) {
        int c = threadIdx.x + k * 256;
        int crow = c >> 4;
        int cq = c & 15;
        if (r0 + crow < N_NODES) {
            uint4 v = *(const uint4*)(so + crow * AROW + cq * 4);
            *(uint4*)(Yb16 + (size_t)(r0 + crow) * 64 + cq * 4) = v;
        }
    }
}

// GEMM2 final variant: fp32 output, no ReLU on output.
__global__ __launch_bounds__(256, 4) void gemm2_final_kernel(const unsigned short* __restrict__ H,
        const float* __restrict__ gsum, const float* __restrict__ gsq,
        const float* __restrict__ gamma, const float* __restrict__ beta,
        const short* __restrict__ Wp, const float* __restrict__ b,
        float* __restrict__ Yf32) {
    __shared__ float s_scale[D];
    __shared__ float s_shift[D];
    __shared__ float sof[64 * 132];   // fp32 tile (33792 B)
    if (threadIdx.x < D) {
        int c = threadIdx.x;
        const float invN = 1.0f / (float)N_NODES;
        float su = 0.f, sq = 0.f;
        #pragma unroll
        for (int pp = 0; pp < NPART; pp++) {
            su += gsum[(size_t)pp * D + c];
            sq += gsq[(size_t)pp * D + c];
        }
        float mu = su * invN;
        float var = fmaxf(sq * invN - mu * mu, 0.f);
        float is = rsqrtf(var + BN_EPS);
        float sc = gamma[c] * is;
        s_scale[c] = sc;
        s_shift[c] = beta[c] - mu * sc;
    }
    __syncthreads();

    int wave = threadIdx.x >> 6, lane = threadIdx.x & 63;
    int r0 = blockIdx.x * 64;
    int m = lane & 15, g = lane >> 4;
    int arow = r0 + wave * 16 + m;
    bool valid = arow < N_NODES;

    short8 a[4];
    #pragma unroll
    for (int kt = 0; kt < 4; kt++) {
        int koff = kt * 32 + g * 8;
        if (valid) {
            short8 hv = *(const short8*)(H + (long long)arow * D + koff);
            unsigned aw[4];
            #pragma unroll
            for (int jj = 0; jj < 4; jj++) {
                float h0 = bf2f((unsigned short)hv[2 * jj]);
                float h1 = bf2f((unsigned short)hv[2 * jj + 1]);
                float v0 = fmaxf(h0 * s_scale[koff + 2 * jj] + s_shift[koff + 2 * jj], 0.f);
                float v1 = fmaxf(h1 * s_scale[koff + 2 * jj + 1] + s_shift[koff + 2 * jj + 1], 0.f);
                aw[jj] = cvtpk(v0, v1);
            }
            a[kt] = __builtin_bit_cast(short8, (uintx4){aw[0], aw[1], aw[2], aw[3]});
        } else {
            a[kt] = (short8)0;
        }
    }

    floatx4 acc[8];
    #pragma unroll
    for (int nt = 0; nt < 8; nt++) acc[nt] = (floatx4){0.f, 0.f, 0.f, 0.f};
    #pragma unroll
    for (int nt = 0; nt < 8; nt++) {
        #pragma unroll
        for (int kt = 0; kt < 4; kt++) {
            short8 bf = *(const short8*)(Wp + (size_t)((kt * 8 + nt) * 64 + lane) * 8);
            acc[nt] = __builtin_amdgcn_mfma_f32_16x16x32_bf16(a[kt], bf, acc[nt], 0, 0, 0);
        }
    }

    #pragma unroll
    for (int nt = 0; nt < 8; nt++) {
        int col = nt * 16 + m;
        float bcol = b[col];
        #pragma unroll
        for (int r = 0; r < 4; r++) {
            int lrow = wave * 16 + g * 4 + r;
            sof[lrow * 132 + col] = acc[nt][r] + bcol;
        }
    }
    __syncthreads();
    // 64 rows x 32 float4 chunks = 2048; 256 threads x 8
    #pragma unroll
    for (int k = 0; k < 8; k++) {
        int c = threadIdx.x + k * 256;
        int crow = c >> 5;
        int cq = c & 31;
        if (r0 + crow < N_NODES) {
            float4 v = *(const float4*)(sof + crow * 132 + cq * 4);
            *(float4*)(Yf32 + (size_t)(r0 + crow) * D + cq * 4) = v;
        }
    }
}

// ---------------------------------------------------------------------------
extern "C" void kernel_launch(void* const* d_in, const int* in_sizes, int n_in,
                              void* d_out, int out_size, void* d_ws, size_t ws_size,
                              hipStream_t stream) {
    const float* x      = (const float*)d_in[0];
    const void*  ei     = d_in[1];
    const float* W1     = (const float*)d_in[2];
    const float* b1     = (const float*)d_in[3];
    const float* gamma  = (const float*)d_in[4];
    const float* beta   = (const float*)d_in[5];
    const float* W2     = (const float*)d_in[6];
    const float* b2     = (const float*)d_in[7];
    const float* epsArr = (const float*)d_in[8];
    float* out = (float*)d_out;

    char* ws = (char*)d_ws;
    const size_t xbuf = (size_t)(N_NODES + 1) * D * sizeof(short);  // +1 pad row
    const size_t hbuf = (size_t)N_NODES * D * sizeof(short);
    unsigned short* Xb  = (unsigned short*)ws;                 // gather input (bf16)
    unsigned* H16       = (unsigned*)(ws + xbuf);              // gemm1 out (bf16 pairs)
    char* p             = ws + xbuf + hbuf;
    short* Wp       = (short*)p;         p += 6 * (size_t)D * D * sizeof(short);
    int* rowptr     = (int*)p;           p += (N_NODES + 1) * sizeof(int);
    int* csr        = (int*)p;           p += (size_t)NBUK * CSTRIDE * sizeof(int);
    unsigned* binned= (unsigned*)p;      p += (size_t)NBUK * BSTRIDE * sizeof(unsigned);
    int* bucketEnd  = (int*)p;           p += NBUK * sizeof(int);
    int* flag       = (int*)p;           p += sizeof(int);
    // zero region: bucketCursor[NBUK] + stats[L][2][NPART][D]
    char* zbase     = p;
    int* bucketCursor=(int*)p;           p += NBUK * sizeof(int);
    float* stats    = (float*)p;         p += (size_t)L_LAYERS * 2 * NPART * D * sizeof(float);
    int zwords      = (int)((p - zbase) / 4);

    // One-time prep: detect edge dtype, zero counters/stats/pad-row, permute
    // weights, convert x -> bf16.
    prep_kernel<<<1 + 48 + (N_NODES * D / 4) / 256, 256, 0, stream>>>(
        x, ei, flag, W1, W2, Wp, Xb, (unsigned*)zbase, zwords);

    // CSR build: 2 dispatches (merged count+bin, then per-bucket padded build).
    bin_kernel<<<NBIN_BLOCKS, 256, 0, stream>>>(ei, flag, bucketCursor, binned);
    csr_build_kernel<<<NBUK, 256, 0, stream>>>(binned, bucketCursor, rowptr, bucketEnd, csr);

    const int g1Grid = N_NODES / 16;                 // 3125, exact (50000/16)
    const int g2Grid = (N_NODES + 63) / 64;
    for (int l = 0; l < L_LAYERS; l++) {
        float* gsum = stats + (size_t)l * 2 * NPART * D;
        float* gsq  = gsum + (size_t)NPART * D;

        gather_gemm1_kernel<<<g1Grid, 256, 0, stream>>>(
            Xb, rowptr, csr, bucketEnd, epsArr, l,
            Wp + (size_t)l * D * D, b1 + (size_t)l * D,
            H16, gsum, gsq);
        if (l == L_LAYERS - 1) {
            gemm2_final_kernel<<<g2Grid, 256, 0, stream>>>(
                (const unsigned short*)H16, gsum, gsq,
                gamma + (size_t)l * D, beta + (size_t)l * D,
                Wp + (size_t)(3 + l) * D * D, b2 + (size_t)l * D, out);
        } else {
            gemm2_mid_kernel<<<g2Grid, 256, 0, stream>>>(
                (const unsigned short*)H16, gsum, gsq,
                gamma + (size_t)l * D, beta + (size_t)l * D,
                Wp + (size_t)(3 + l) * D * D, b2 + (size_t)l * D, (unsigned*)Xb);
        }
    }
}